// Round 6
// baseline (654.515 us; speedup 1.0000x reference)
//
#include <hip/hip_runtime.h>
#include <hip/hip_bf16.h>

#define U_CNT 100000
#define I_CNT 50000
#define N_CNT 150000   // U + I
#define K_DIM 64
#define CT_STRIDE 128                     // 64 C + 64 T bf16 per node row
#define E_CNT 500000
#define F_DIM 64
#define N_LAYERS 3
#define B_CNT 100000
#define NBLK_SCAN ((N_CNT + 255) / 256)   // 586
#define EP_TILES (E_CNT / 16)             // 31250 (exact)
#define EP_BLOCKS 2048

typedef __hip_bfloat16 bf16;
typedef __attribute__((ext_vector_type(8))) short short8;
typedef __attribute__((ext_vector_type(4))) float f32x4;

__device__ __forceinline__ float u2f(unsigned short u) {
    return __uint_as_float(((unsigned)u) << 16);
}
__device__ __forceinline__ unsigned short f2u(float x) {
    bf16 h = __float2bfloat16(x);           // RNE
    return *reinterpret_cast<unsigned short*>(&h);
}

// --- int degree count over both endpoints -----------------------------------
__global__ __launch_bounds__(256) void cnt_kernel(const int* __restrict__ rows,
                                                  const int* __restrict__ cols,
                                                  int* __restrict__ cnt) {
    int e = blockIdx.x * blockDim.x + threadIdx.x;
    if (e < E_CNT) {
        atomicAdd(&cnt[rows[e]], 1);
        atomicAdd(&cnt[cols[e]], 1);
    }
}

// --- dinv[n] = deg>0 ? rsqrt(deg) : 0 ---------------------------------------
__global__ __launch_bounds__(256) void dinv_kernel(const int* __restrict__ cnt,
                                                   float* __restrict__ dinv) {
    int n = blockIdx.x * blockDim.x + threadIdx.x;
    if (n < N_CNT) {
        int c = cnt[n];
        dinv[n] = (c > 0) ? rsqrtf((float)c) : 0.0f;
    }
}

// --- hierarchical exclusive scan --------------------------------------------
__global__ __launch_bounds__(256) void scanA_kernel(const int* __restrict__ cnt,
                                                    int* __restrict__ bsum) {
    __shared__ int sd[256];
    int tid = threadIdx.x;
    int i = blockIdx.x * 256 + tid;
    sd[tid] = (i < N_CNT) ? cnt[i] : 0;
    __syncthreads();
    for (int off = 128; off > 0; off >>= 1) {
        if (tid < off) sd[tid] += sd[tid + off];
        __syncthreads();
    }
    if (tid == 0) bsum[blockIdx.x] = sd[0];
}

__global__ __launch_bounds__(1024) void scanB_kernel(const int* __restrict__ bsum,
                                                     int* __restrict__ boff) {
    __shared__ int sd[1024];
    int tid = threadIdx.x;
    int v = (tid < NBLK_SCAN) ? bsum[tid] : 0;
    sd[tid] = v;
    __syncthreads();
    for (int off = 1; off < 1024; off <<= 1) {
        int t = 0;
        if (tid >= off) t = sd[tid - off];
        __syncthreads();
        if (tid >= off) sd[tid] += t;
        __syncthreads();
    }
    if (tid < NBLK_SCAN) boff[tid] = sd[tid] - v;
}

__global__ __launch_bounds__(256) void scanC_kernel(const int* __restrict__ cnt,
                                                    const int* __restrict__ boff,
                                                    int* __restrict__ offs,
                                                    int* __restrict__ cursor) {
    __shared__ int sd[256];
    int tid = threadIdx.x;
    int i = blockIdx.x * 256 + tid;
    int v = (i < N_CNT) ? cnt[i] : 0;
    sd[tid] = v;
    __syncthreads();
    for (int off = 1; off < 256; off <<= 1) {
        int t = 0;
        if (tid >= off) t = sd[tid - off];
        __syncthreads();
        if (tid >= off) sd[tid] += t;
        __syncthreads();
    }
    if (i < N_CNT) {
        int ex = boff[blockIdx.x] + sd[tid] - v;
        offs[i] = ex;
        cursor[i] = ex;
    }
    if (blockIdx.x == 0 && tid == 0) offs[N_CNT] = 2 * E_CNT;
}

// --- scatter directed edges into CSR slots: packed {src, eid} ---------------
__global__ __launch_bounds__(256) void scatter_kernel(const int* __restrict__ rows,
                                                      const int* __restrict__ cols,
                                                      int* __restrict__ cursor,
                                                      int2* __restrict__ eidx) {
    int d = blockIdx.x * blockDim.x + threadIdx.x;
    if (d >= 2 * E_CNT) return;
    int eid = (d < E_CNT) ? d : d - E_CNT;
    int src = (d < E_CNT) ? rows[eid] : cols[eid];
    int dst = (d < E_CNT) ? cols[eid] : rows[eid];
    int pos = atomicAdd(&cursor[dst], 1);
    eidx[pos] = make_int2(src, eid);
}

// --- prepack W into MFMA B-frag layout (bf16) -------------------------------
// Wb[(((s*4+t)*4+quad)*16+m15)*8+j] = bf16(W[(s*32+quad*8+j)*64 + t*16+m15])
__global__ __launch_bounds__(256) void wprep_kernel(const float* __restrict__ W,
                                                    unsigned short* __restrict__ Wb) {
    int tid = blockIdx.x * blockDim.x + threadIdx.x;
    if (tid >= 4096) return;
    int j = tid & 7;
    int m15 = (tid >> 3) & 15;
    int quad = (tid >> 7) & 3;
    int t = (tid >> 9) & 3;
    int s = (tid >> 11) & 1;
    Wb[tid] = f2u(W[(s * 32 + quad * 8 + j) * K_DIM + t * 16 + m15]);
}

// --- edge projection via MFMA: epw = (ef @ W + b) * nrm, bf16 ---------------
// 16-edge x 64-col tiles; K=F=64 as 2 mfma_f32_16x16x32_bf16 steps.
// A-frag: A[m=lane&15][k=quad*8+j] -> 32B contiguous load per lane from ef.
// B-frag: prepacked Wb, 8x dwordx4 per wave. C/D: row=quad*4+reg, col=lane&15.
__global__ __launch_bounds__(256) void ep_kernel(const float* __restrict__ ef,
                                                 const unsigned short* __restrict__ Wb,
                                                 const float* __restrict__ bias,
                                                 const int* __restrict__ rows,
                                                 const int* __restrict__ cols,
                                                 const float* __restrict__ dinv,
                                                 bf16* __restrict__ epw) {
    int lane = threadIdx.x & 63;
    int wv = threadIdx.x >> 6;
    int m15 = lane & 15;
    int quad = lane >> 4;

    short8 bfrag[2][4];
    #pragma unroll
    for (int s = 0; s < 2; s++) {
        #pragma unroll
        for (int t = 0; t < 4; t++) {
            bfrag[s][t] = *(const short8*)(Wb + (size_t)((((s * 4 + t) * 4 + quad) * 16 + m15) * 8));
        }
    }
    float bv[4];
    #pragma unroll
    for (int t = 0; t < 4; t++) bv[t] = bias[t * 16 + m15];

    for (int tile = blockIdx.x * 4 + wv; tile < EP_TILES; tile += EP_BLOCKS * 4) {
        int e0 = tile * 16;
        float wlane = 0.0f;
        if (lane < 16) {
            int e = e0 + lane;
            wlane = dinv[rows[e]] * dinv[cols[e]];
        }
        float wrow[4];
        #pragma unroll
        for (int r = 0; r < 4; r++) wrow[r] = __shfl(wlane, quad * 4 + r, 64);

        short8 afrag[2];
        #pragma unroll
        for (int s = 0; s < 2; s++) {
            const float* src = ef + (size_t)(e0 + m15) * F_DIM + s * 32 + quad * 8;
            float4 lo = *(const float4*)src;
            float4 hi = *(const float4*)(src + 4);
            short8 a;
            a[0] = (short)f2u(lo.x); a[1] = (short)f2u(lo.y);
            a[2] = (short)f2u(lo.z); a[3] = (short)f2u(lo.w);
            a[4] = (short)f2u(hi.x); a[5] = (short)f2u(hi.y);
            a[6] = (short)f2u(hi.z); a[7] = (short)f2u(hi.w);
            afrag[s] = a;
        }

        f32x4 acc[4];
        #pragma unroll
        for (int t = 0; t < 4; t++) acc[t] = (f32x4){0.0f, 0.0f, 0.0f, 0.0f};
        #pragma unroll
        for (int s = 0; s < 2; s++) {
            #pragma unroll
            for (int t = 0; t < 4; t++) {
                acc[t] = __builtin_amdgcn_mfma_f32_16x16x32_bf16(
                    afrag[s], bfrag[s][t], acc[t], 0, 0, 0);
            }
        }
        #pragma unroll
        for (int t = 0; t < 4; t++) {
            #pragma unroll
            for (int r = 0; r < 4; r++) {
                int e = e0 + quad * 4 + r;
                float v = (acc[t][r] + bv[t]) * wrow[r];
                epw[(size_t)e * K_DIM + t * 16 + m15] = __float2bfloat16(v);
            }
        }
    }
}

// --- init interleaved CT table: C = dinv*concat(Gu,Gi) (scaled form),
//     T = concat(Gut,Git) (plain) -------------------------------------------
__global__ __launch_bounds__(256) void init_kernel(const float4* __restrict__ Gu,
                                                   const float4* __restrict__ Gi,
                                                   const float4* __restrict__ Gut,
                                                   const float4* __restrict__ Git,
                                                   const float* __restrict__ dinv,
                                                   unsigned short* __restrict__ CT) {
    int idx = blockIdx.x * blockDim.x + threadIdx.x;   // node*16 + q
    const int NQ = N_CNT * 16;
    if (idx >= NQ) return;
    int n = idx >> 4;
    int q = idx & 15;
    const int UQ = U_CNT * 16;
    float4 c = (idx < UQ) ? Gu[idx] : Gi[idx - UQ];
    float4 t = (idx < UQ) ? Gut[idx] : Git[idx - UQ];
    float dv = dinv[n];
    ushort4 co, to;
    co.x = f2u(c.x * dv); co.y = f2u(c.y * dv);
    co.z = f2u(c.z * dv); co.w = f2u(c.w * dv);
    to.x = f2u(t.x); to.y = f2u(t.y); to.z = f2u(t.z); to.w = f2u(t.w);
    *(ushort4*)(CT + (size_t)n * CT_STRIDE + q * 4) = co;
    *(ushort4*)(CT + (size_t)n * CT_STRIDE + 64 + q * 4) = to;
}

// --- one propagation layer, gather-only, software-pipelined -----------------
// Wave per node; sub = lane>>4 handles edge p+sub (+4 for group B), q = lane&15
// owns a 4-col chunk. Collab is unweighted row-sum of scaled table; epilogue
// scales by dinv^2 (intermediate) or dinv (last). Textual: epw (w folded).
__global__ __launch_bounds__(256) void prop_kernel(const int* __restrict__ offs,
                                                   const int2* __restrict__ eidx,
                                                   const bf16* __restrict__ epw,
                                                   const unsigned short* __restrict__ CTin,
                                                   unsigned short* __restrict__ CTout,
                                                   const float* __restrict__ dinv,
                                                   int last) {
    int gt = blockIdx.x * blockDim.x + threadIdx.x;
    int n = gt >> 6;
    if (n >= N_CNT) return;
    int lane = threadIdx.x & 63;
    int sub = lane >> 4;
    int q = lane & 15;
    int p0 = offs[n];
    int p1 = offs[n + 1];
    float accC[4] = {0.0f, 0.0f, 0.0f, 0.0f};
    float accT[4] = {0.0f, 0.0f, 0.0f, 0.0f};
    for (int p = p0; p < p1; p += 8) {
        int peA = p + sub;
        int peB = p + 4 + sub;
        ushort4 cA = {0, 0, 0, 0}, tA = {0, 0, 0, 0}, eA = {0, 0, 0, 0};
        ushort4 cB = {0, 0, 0, 0}, tB = {0, 0, 0, 0}, eB = {0, 0, 0, 0};
        if (peA < p1) {
            int2 m = eidx[peA];
            const unsigned short* rb = CTin + (size_t)m.x * CT_STRIDE;
            cA = *(const ushort4*)(rb + q * 4);
            tA = *(const ushort4*)(rb + 64 + q * 4);
            eA = *(const ushort4*)((const unsigned short*)epw + ((size_t)m.y << 6) + (q << 2));
        }
        if (peB < p1) {
            int2 m = eidx[peB];
            const unsigned short* rb = CTin + (size_t)m.x * CT_STRIDE;
            cB = *(const ushort4*)(rb + q * 4);
            tB = *(const ushort4*)(rb + 64 + q * 4);
            eB = *(const ushort4*)((const unsigned short*)epw + ((size_t)m.y << 6) + (q << 2));
        }
        accC[0] += u2f(cA.x) + u2f(cB.x);
        accC[1] += u2f(cA.y) + u2f(cB.y);
        accC[2] += u2f(cA.z) + u2f(cB.z);
        accC[3] += u2f(cA.w) + u2f(cB.w);
        accT[0] = fmaf(u2f(eA.x), u2f(tA.x), fmaf(u2f(eB.x), u2f(tB.x), accT[0]));
        accT[1] = fmaf(u2f(eA.y), u2f(tA.y), fmaf(u2f(eB.y), u2f(tB.y), accT[1]));
        accT[2] = fmaf(u2f(eA.z), u2f(tA.z), fmaf(u2f(eB.z), u2f(tB.z), accT[2]));
        accT[3] = fmaf(u2f(eA.w), u2f(tA.w), fmaf(u2f(eB.w), u2f(tB.w), accT[3]));
    }
    #pragma unroll
    for (int i = 0; i < 4; i++) {
        accC[i] += __shfl_down(accC[i], 32, 64);
        accC[i] += __shfl_down(accC[i], 16, 64);
        accT[i] += __shfl_down(accT[i], 32, 64);
        accT[i] += __shfl_down(accT[i], 16, 64);
    }
    if (lane < 16) {
        float dv = dinv[n];
        float sc = last ? dv : dv * dv;
        ushort4 oc, ot;
        oc.x = f2u(accC[0] * sc); oc.y = f2u(accC[1] * sc);
        oc.z = f2u(accC[2] * sc); oc.w = f2u(accC[3] * sc);
        ot.x = f2u(accT[0]); ot.y = f2u(accT[1]);
        ot.z = f2u(accT[2]); ot.w = f2u(accT[3]);
        *(ushort4*)(CTout + (size_t)n * CT_STRIDE + q * 4) = oc;
        *(ushort4*)(CTout + (size_t)n * CT_STRIDE + 64 + q * 4) = ot;
    }
}

// --- scoring: wave per query, 64-lane shuffle reduction ---------------------
__global__ __launch_bounds__(256) void score_kernel(const int* __restrict__ users,
                                                    const int* __restrict__ items,
                                                    const unsigned short* __restrict__ CT,
                                                    const float* __restrict__ Bu,
                                                    const float* __restrict__ Bi,
                                                    const float* __restrict__ But,
                                                    const float* __restrict__ Bit,
                                                    const float* __restrict__ Mu,
                                                    float* __restrict__ out) {
    int gt = blockIdx.x * blockDim.x + threadIdx.x;
    int b = gt >> 6;
    int k = threadIdx.x & 63;
    if (b >= B_CNT) return;
    int u = users[b];
    int it = items[b];
    const unsigned short* ru = CT + (size_t)u * CT_STRIDE;
    const unsigned short* ri = CT + (size_t)(U_CNT + it) * CT_STRIDE;
    float v = u2f(ru[k]) * u2f(ri[k]) + u2f(ru[64 + k]) * u2f(ri[64 + k]);
    #pragma unroll
    for (int off = 32; off > 0; off >>= 1) {
        v += __shfl_down(v, off, 64);
    }
    if (k == 0) {
        v += Bu[u] + Bi[it] + But[u] + Bit[it] + Mu[0];
        out[b] = v;
    }
}

extern "C" void kernel_launch(void* const* d_in, const int* in_sizes, int n_in,
                              void* d_out, int out_size, void* d_ws, size_t ws_size,
                              hipStream_t stream) {
    const float* Gu   = (const float*)d_in[0];
    const float* Gi   = (const float*)d_in[1];
    const float* Gut  = (const float*)d_in[2];
    const float* Git  = (const float*)d_in[3];
    const float* Bu   = (const float*)d_in[4];
    const float* Bi   = (const float*)d_in[5];
    const float* But  = (const float*)d_in[6];
    const float* Bit  = (const float*)d_in[7];
    const float* Mu   = (const float*)d_in[8];
    const float* W    = (const float*)d_in[9];
    const float* bpj  = (const float*)d_in[10];
    const float* ef   = (const float*)d_in[11];
    const int* rows   = (const int*)d_in[12];
    const int* cols   = (const int*)d_in[13];
    const int* users  = (const int*)d_in[14];
    const int* items  = (const int*)d_in[15];
    float* out = (float*)d_out;

    const size_t EK = (size_t)E_CNT * K_DIM;
    const size_t NCT = (size_t)N_CNT * CT_STRIDE;

    char* wp = (char*)d_ws;
    auto alloc = [&](size_t bytes) {
        char* r = wp;
        wp += (bytes + 255) & ~(size_t)255;
        return r;
    };
    bf16* epw    = (bf16*)alloc(EK * sizeof(bf16));            // 64 MB
    unsigned short* CT0 = (unsigned short*)alloc(NCT * 2);     // 38.4 MB
    unsigned short* CT1 = (unsigned short*)alloc(NCT * 2);     // 38.4 MB
    float* dinv  = (float*)alloc(N_CNT * sizeof(float));
    int* cnt     = (int*)alloc(N_CNT * sizeof(int));
    int* offs    = (int*)alloc((N_CNT + 1) * sizeof(int));
    int* cursor  = (int*)alloc(N_CNT * sizeof(int));
    int2* eidx   = (int2*)alloc(2 * E_CNT * sizeof(int2));     // 8 MB
    unsigned short* Wb = (unsigned short*)alloc(4096 * sizeof(unsigned short));
    int* bsum    = (int*)alloc(NBLK_SCAN * sizeof(int));
    int* boff    = (int*)alloc(NBLK_SCAN * sizeof(int));

    hipMemsetAsync(cnt, 0, N_CNT * sizeof(int), stream);
    cnt_kernel<<<(E_CNT + 255) / 256, 256, 0, stream>>>(rows, cols, cnt);
    dinv_kernel<<<(N_CNT + 255) / 256, 256, 0, stream>>>(cnt, dinv);
    scanA_kernel<<<NBLK_SCAN, 256, 0, stream>>>(cnt, bsum);
    scanB_kernel<<<1, 1024, 0, stream>>>(bsum, boff);
    scanC_kernel<<<NBLK_SCAN, 256, 0, stream>>>(cnt, boff, offs, cursor);
    scatter_kernel<<<(2 * E_CNT + 255) / 256, 256, 0, stream>>>(rows, cols, cursor, eidx);
    wprep_kernel<<<16, 256, 0, stream>>>(W, Wb);
    ep_kernel<<<EP_BLOCKS, 256, 0, stream>>>(ef, Wb, bpj, rows, cols, dinv, epw);
    init_kernel<<<(N_CNT * 16 + 255) / 256, 256, 0, stream>>>(
        (const float4*)Gu, (const float4*)Gi, (const float4*)Gut, (const float4*)Git,
        dinv, CT0);

    unsigned short* CTs[2] = {CT0, CT1};
    int cur = 0;
    for (int l = 0; l < N_LAYERS; l++) {
        prop_kernel<<<(N_CNT * 64 + 255) / 256, 256, 0, stream>>>(
            offs, eidx, epw, CTs[cur], CTs[1 - cur], dinv, (l == N_LAYERS - 1) ? 1 : 0);
        cur = 1 - cur;
    }

    score_kernel<<<(B_CNT * 64 + 255) / 256, 256, 0, stream>>>(
        users, items, CTs[cur], Bu, Bi, But, Bit, Mu, out);
}

// Round 7
// 652.914 us; speedup vs baseline: 1.0025x; 1.0025x over previous
//
#include <hip/hip_runtime.h>
#include <hip/hip_bf16.h>

#define U_CNT 100000
#define I_CNT 50000
#define N_CNT 150000   // U + I
#define K_DIM 64
#define CT_STRIDE 128                     // 64 C + 64 T bf16 per node row
#define E_CNT 500000
#define F_DIM 64
#define N_LAYERS 3
#define B_CNT 100000
#define NBLK_SCAN ((N_CNT + 255) / 256)   // 586
#define EP_TILES (E_CNT / 16)             // 31250 (exact)
#define EP_BLOCKS 2048

typedef __hip_bfloat16 bf16;
typedef __attribute__((ext_vector_type(8))) short short8;
typedef __attribute__((ext_vector_type(4))) float f32x4;
typedef unsigned short u16;

__device__ __forceinline__ float u2f(u16 u) {
    return __uint_as_float(((unsigned)u) << 16);
}
__device__ __forceinline__ u16 f2u(float x) {
    bf16 h = __float2bfloat16(x);           // RNE
    return *reinterpret_cast<u16*>(&h);
}

// --- int degree count over both endpoints -----------------------------------
__global__ __launch_bounds__(256) void cnt_kernel(const int* __restrict__ rows,
                                                  const int* __restrict__ cols,
                                                  int* __restrict__ cnt) {
    int e = blockIdx.x * blockDim.x + threadIdx.x;
    if (e < E_CNT) {
        atomicAdd(&cnt[rows[e]], 1);
        atomicAdd(&cnt[cols[e]], 1);
    }
}

// --- scan phase A: per-block sums; also emits dinv --------------------------
__global__ __launch_bounds__(256) void scanA_kernel(const int* __restrict__ cnt,
                                                    int* __restrict__ bsum,
                                                    float* __restrict__ dinv) {
    __shared__ int sd[256];
    int tid = threadIdx.x;
    int i = blockIdx.x * 256 + tid;
    int c = (i < N_CNT) ? cnt[i] : 0;
    if (i < N_CNT) dinv[i] = (c > 0) ? rsqrtf((float)c) : 0.0f;
    sd[tid] = c;
    __syncthreads();
    for (int off = 128; off > 0; off >>= 1) {
        if (tid < off) sd[tid] += sd[tid + off];
        __syncthreads();
    }
    if (tid == 0) bsum[blockIdx.x] = sd[0];
}

__global__ __launch_bounds__(1024) void scanB_kernel(const int* __restrict__ bsum,
                                                     int* __restrict__ boff) {
    __shared__ int sd[1024];
    int tid = threadIdx.x;
    int v = (tid < NBLK_SCAN) ? bsum[tid] : 0;
    sd[tid] = v;
    __syncthreads();
    for (int off = 1; off < 1024; off <<= 1) {
        int t = 0;
        if (tid >= off) t = sd[tid - off];
        __syncthreads();
        if (tid >= off) sd[tid] += t;
        __syncthreads();
    }
    if (tid < NBLK_SCAN) boff[tid] = sd[tid] - v;
}

__global__ __launch_bounds__(256) void scanC_kernel(const int* __restrict__ cnt,
                                                    const int* __restrict__ boff,
                                                    int* __restrict__ offs,
                                                    int* __restrict__ cursor) {
    __shared__ int sd[256];
    int tid = threadIdx.x;
    int i = blockIdx.x * 256 + tid;
    int v = (i < N_CNT) ? cnt[i] : 0;
    sd[tid] = v;
    __syncthreads();
    for (int off = 1; off < 256; off <<= 1) {
        int t = 0;
        if (tid >= off) t = sd[tid - off];
        __syncthreads();
        if (tid >= off) sd[tid] += t;
        __syncthreads();
    }
    if (i < N_CNT) {
        int ex = boff[blockIdx.x] + sd[tid] - v;
        offs[i] = ex;
        cursor[i] = ex;
    }
    if (blockIdx.x == 0 && tid == 0) offs[N_CNT] = 2 * E_CNT;
}

// --- scatter: CSR slots get src node; record each directed edge's slot ------
// d < E: (src=rows, dst=cols) -> slot0[d]; else (src=cols, dst=rows) -> slot1.
__global__ __launch_bounds__(256) void scatter_kernel(const int* __restrict__ rows,
                                                      const int* __restrict__ cols,
                                                      int* __restrict__ cursor,
                                                      int* __restrict__ esrc,
                                                      int* __restrict__ slot0,
                                                      int* __restrict__ slot1) {
    int d = blockIdx.x * blockDim.x + threadIdx.x;
    if (d >= 2 * E_CNT) return;
    int eid = (d < E_CNT) ? d : d - E_CNT;
    int src = (d < E_CNT) ? rows[eid] : cols[eid];
    int dst = (d < E_CNT) ? cols[eid] : rows[eid];
    int pos = atomicAdd(&cursor[dst], 1);
    esrc[pos] = src;
    if (d < E_CNT) slot0[eid] = pos;
    else           slot1[eid] = pos;
}

// --- prepack W into MFMA B-frag layout (bf16) -------------------------------
__global__ __launch_bounds__(256) void wprep_kernel(const float* __restrict__ W,
                                                    u16* __restrict__ Wb) {
    int tid = blockIdx.x * blockDim.x + threadIdx.x;
    if (tid >= 4096) return;
    int j = tid & 7;
    int m15 = (tid >> 3) & 15;
    int quad = (tid >> 7) & 3;
    int t = (tid >> 9) & 3;
    int s = (tid >> 11) & 1;
    Wb[tid] = f2u(W[(s * 32 + quad * 8 + j) * K_DIM + t * 16 + m15]);
}

// --- edge projection via MFMA, written straight into BOTH CSR slots ---------
// 16-edge x 64-col tiles, 2x mfma_f32_16x16x32_bf16. Epilogue: transpose tile
// through wave-private LDS (row stride 68 u16 = 136 B -> conflict-free b64
// reads), then write each edge row (128 B) to slot0[e] and slot1[e] of epw2.
__global__ __launch_bounds__(256) void ep_kernel(const float* __restrict__ ef,
                                                 const u16* __restrict__ Wb,
                                                 const float* __restrict__ bias,
                                                 const int* __restrict__ rows,
                                                 const int* __restrict__ cols,
                                                 const float* __restrict__ dinv,
                                                 const int* __restrict__ slot0,
                                                 const int* __restrict__ slot1,
                                                 u16* __restrict__ epw2) {
    __shared__ u16 sT[4][16][68];
    int lane = threadIdx.x & 63;
    int wv = threadIdx.x >> 6;
    int m15 = lane & 15;
    int quad = lane >> 4;

    short8 bfrag[2][4];
    #pragma unroll
    for (int s = 0; s < 2; s++) {
        #pragma unroll
        for (int t = 0; t < 4; t++) {
            bfrag[s][t] = *(const short8*)(Wb + (size_t)((((s * 4 + t) * 4 + quad) * 16 + m15) * 8));
        }
    }
    float bv[4];
    #pragma unroll
    for (int t = 0; t < 4; t++) bv[t] = bias[t * 16 + m15];

    for (int tile = blockIdx.x * 4 + wv; tile < EP_TILES; tile += EP_BLOCKS * 4) {
        int e0 = tile * 16;
        float wlane = 0.0f;
        if (lane < 16) {
            int e = e0 + lane;
            wlane = dinv[rows[e]] * dinv[cols[e]];
        }
        float wrow[4];
        #pragma unroll
        for (int r = 0; r < 4; r++) wrow[r] = __shfl(wlane, quad * 4 + r, 64);

        short8 afrag[2];
        #pragma unroll
        for (int s = 0; s < 2; s++) {
            const float* src = ef + (size_t)(e0 + m15) * F_DIM + s * 32 + quad * 8;
            float4 lo = *(const float4*)src;
            float4 hi = *(const float4*)(src + 4);
            short8 a;
            a[0] = (short)f2u(lo.x); a[1] = (short)f2u(lo.y);
            a[2] = (short)f2u(lo.z); a[3] = (short)f2u(lo.w);
            a[4] = (short)f2u(hi.x); a[5] = (short)f2u(hi.y);
            a[6] = (short)f2u(hi.z); a[7] = (short)f2u(hi.w);
            afrag[s] = a;
        }

        f32x4 acc[4];
        #pragma unroll
        for (int t = 0; t < 4; t++) acc[t] = (f32x4){0.0f, 0.0f, 0.0f, 0.0f};
        #pragma unroll
        for (int s = 0; s < 2; s++) {
            #pragma unroll
            for (int t = 0; t < 4; t++) {
                acc[t] = __builtin_amdgcn_mfma_f32_16x16x32_bf16(
                    afrag[s], bfrag[s][t], acc[t], 0, 0, 0);
            }
        }
        // stage tile rows in wave-private LDS (wave-synchronous, no barrier)
        #pragma unroll
        for (int t = 0; t < 4; t++) {
            #pragma unroll
            for (int r = 0; r < 4; r++) {
                sT[wv][quad * 4 + r][t * 16 + m15] =
                    f2u((acc[t][r] + bv[t]) * wrow[r]);
            }
        }
        // write 16 rows x 2 slots, 4 rows per pass (ushort4 per lane)
        #pragma unroll
        for (int pp = 0; pp < 4; pp++) {
            int row = pp * 4 + quad;            // quad = row-in-pass
            ushort4 v = *(const ushort4*)&sT[wv][row][m15 * 4];
            int e = e0 + row;
            int sA = slot0[e];
            int sB = slot1[e];
            *(ushort4*)(epw2 + (size_t)sA * K_DIM + m15 * 4) = v;
            *(ushort4*)(epw2 + (size_t)sB * K_DIM + m15 * 4) = v;
        }
    }
}

// --- init interleaved CT table: C = dinv*collab (scaled form), T plain ------
__global__ __launch_bounds__(256) void init_kernel(const float4* __restrict__ Gu,
                                                   const float4* __restrict__ Gi,
                                                   const float4* __restrict__ Gut,
                                                   const float4* __restrict__ Git,
                                                   const float* __restrict__ dinv,
                                                   u16* __restrict__ CT) {
    int idx = blockIdx.x * blockDim.x + threadIdx.x;   // node*16 + q
    const int NQ = N_CNT * 16;
    if (idx >= NQ) return;
    int n = idx >> 4;
    int q = idx & 15;
    const int UQ = U_CNT * 16;
    float4 c = (idx < UQ) ? Gu[idx] : Gi[idx - UQ];
    float4 t = (idx < UQ) ? Gut[idx] : Git[idx - UQ];
    float dv = dinv[n];
    ushort4 co, to;
    co.x = f2u(c.x * dv); co.y = f2u(c.y * dv);
    co.z = f2u(c.z * dv); co.w = f2u(c.w * dv);
    to.x = f2u(t.x); to.y = f2u(t.y); to.z = f2u(t.z); to.w = f2u(t.w);
    *(ushort4*)(CT + (size_t)n * CT_STRIDE + q * 4) = co;
    *(ushort4*)(CT + (size_t)n * CT_STRIDE + 64 + q * 4) = to;
}

// --- one propagation layer: 2 random gathers + 1 streamed read per edge -----
// Wave per node; sub = lane>>4 edge, q = lane&15 col-chunk. epw2 is in CSR
// slot order -> epw2[pe*64] reads are sequential (512 B contiguous per instr).
// Collab: unweighted row-sum of scaled table; epilogue x dinv^2 (or dinv last).
__global__ __launch_bounds__(256) void prop_kernel(const int* __restrict__ offs,
                                                   const int* __restrict__ esrc,
                                                   const u16* __restrict__ epw2,
                                                   const u16* __restrict__ CTin,
                                                   u16* __restrict__ CTout,
                                                   const float* __restrict__ dinv,
                                                   int last) {
    int gt = blockIdx.x * blockDim.x + threadIdx.x;
    int n = gt >> 6;
    if (n >= N_CNT) return;
    int lane = threadIdx.x & 63;
    int sub = lane >> 4;
    int q = lane & 15;
    int p0 = offs[n];
    int p1 = offs[n + 1];
    float accC[4] = {0.0f, 0.0f, 0.0f, 0.0f};
    float accT[4] = {0.0f, 0.0f, 0.0f, 0.0f};
    for (int p = p0; p < p1; p += 4) {
        int pe = p + sub;
        if (pe < p1) {
            int s = esrc[pe];
            const u16* rb = CTin + (size_t)s * CT_STRIDE;
            ushort4 cv = *(const ushort4*)(rb + q * 4);
            ushort4 tv = *(const ushort4*)(rb + 64 + q * 4);
            ushort4 ev = *(const ushort4*)(epw2 + (size_t)pe * K_DIM + q * 4);
            accC[0] += u2f(cv.x);
            accC[1] += u2f(cv.y);
            accC[2] += u2f(cv.z);
            accC[3] += u2f(cv.w);
            accT[0] = fmaf(u2f(ev.x), u2f(tv.x), accT[0]);
            accT[1] = fmaf(u2f(ev.y), u2f(tv.y), accT[1]);
            accT[2] = fmaf(u2f(ev.z), u2f(tv.z), accT[2]);
            accT[3] = fmaf(u2f(ev.w), u2f(tv.w), accT[3]);
        }
    }
    #pragma unroll
    for (int i = 0; i < 4; i++) {
        accC[i] += __shfl_down(accC[i], 32, 64);
        accC[i] += __shfl_down(accC[i], 16, 64);
        accT[i] += __shfl_down(accT[i], 32, 64);
        accT[i] += __shfl_down(accT[i], 16, 64);
    }
    if (lane < 16) {
        float dv = dinv[n];
        float sc = last ? dv : dv * dv;
        ushort4 oc, ot;
        oc.x = f2u(accC[0] * sc); oc.y = f2u(accC[1] * sc);
        oc.z = f2u(accC[2] * sc); oc.w = f2u(accC[3] * sc);
        ot.x = f2u(accT[0]); ot.y = f2u(accT[1]);
        ot.z = f2u(accT[2]); ot.w = f2u(accT[3]);
        *(ushort4*)(CTout + (size_t)n * CT_STRIDE + q * 4) = oc;
        *(ushort4*)(CTout + (size_t)n * CT_STRIDE + 64 + q * 4) = ot;
    }
}

// --- scoring: wave per query; lanes 0-31 cover C, 32-63 cover T -------------
__global__ __launch_bounds__(256) void score_kernel(const int* __restrict__ users,
                                                    const int* __restrict__ items,
                                                    const u16* __restrict__ CT,
                                                    const float* __restrict__ Bu,
                                                    const float* __restrict__ Bi,
                                                    const float* __restrict__ But,
                                                    const float* __restrict__ Bit,
                                                    const float* __restrict__ Mu,
                                                    float* __restrict__ out) {
    int gt = blockIdx.x * blockDim.x + threadIdx.x;
    int b = gt >> 6;
    if (b >= B_CNT) return;
    int lane = threadIdx.x & 63;
    int off = (lane >> 5) * 64 + (lane & 31) * 2;   // C half or T half
    int u = users[b];
    int it = items[b];
    const u16* ru = CT + (size_t)u * CT_STRIDE;
    const u16* ri = CT + (size_t)(U_CNT + it) * CT_STRIDE;
    ushort2 au = *(const ushort2*)(ru + off);
    ushort2 ai = *(const ushort2*)(ri + off);
    float v = u2f(au.x) * u2f(ai.x) + u2f(au.y) * u2f(ai.y);
    #pragma unroll
    for (int o = 32; o > 0; o >>= 1) {
        v += __shfl_down(v, o, 64);
    }
    if (lane == 0) {
        v += Bu[u] + Bi[it] + But[u] + Bit[it] + Mu[0];
        out[b] = v;
    }
}

extern "C" void kernel_launch(void* const* d_in, const int* in_sizes, int n_in,
                              void* d_out, int out_size, void* d_ws, size_t ws_size,
                              hipStream_t stream) {
    const float* Gu   = (const float*)d_in[0];
    const float* Gi   = (const float*)d_in[1];
    const float* Gut  = (const float*)d_in[2];
    const float* Git  = (const float*)d_in[3];
    const float* Bu   = (const float*)d_in[4];
    const float* Bi   = (const float*)d_in[5];
    const float* But  = (const float*)d_in[6];
    const float* Bit  = (const float*)d_in[7];
    const float* Mu   = (const float*)d_in[8];
    const float* W    = (const float*)d_in[9];
    const float* bpj  = (const float*)d_in[10];
    const float* ef   = (const float*)d_in[11];
    const int* rows   = (const int*)d_in[12];
    const int* cols   = (const int*)d_in[13];
    const int* users  = (const int*)d_in[14];
    const int* items  = (const int*)d_in[15];
    float* out = (float*)d_out;

    const size_t NCT = (size_t)N_CNT * CT_STRIDE;

    char* wp = (char*)d_ws;
    auto alloc = [&](size_t bytes) {
        char* r = wp;
        wp += (bytes + 255) & ~(size_t)255;
        return r;
    };
    u16* epw2   = (u16*)alloc((size_t)2 * E_CNT * K_DIM * 2);  // 128 MB
    u16* CT0    = (u16*)alloc(NCT * 2);                        // 38.4 MB
    u16* CT1    = (u16*)alloc(NCT * 2);                        // 38.4 MB
    float* dinv = (float*)alloc(N_CNT * sizeof(float));
    int* cnt    = (int*)alloc(N_CNT * sizeof(int));
    int* offs   = (int*)alloc((N_CNT + 1) * sizeof(int));
    int* cursor = (int*)alloc(N_CNT * sizeof(int));
    int* esrc   = (int*)alloc(2 * E_CNT * sizeof(int));        // 4 MB
    int* slot0  = (int*)alloc(E_CNT * sizeof(int));            // 2 MB
    int* slot1  = (int*)alloc(E_CNT * sizeof(int));            // 2 MB
    u16* Wb     = (u16*)alloc(4096 * sizeof(u16));
    int* bsum   = (int*)alloc(NBLK_SCAN * sizeof(int));
    int* boff   = (int*)alloc(NBLK_SCAN * sizeof(int));

    hipMemsetAsync(cnt, 0, N_CNT * sizeof(int), stream);
    cnt_kernel<<<(E_CNT + 255) / 256, 256, 0, stream>>>(rows, cols, cnt);
    scanA_kernel<<<NBLK_SCAN, 256, 0, stream>>>(cnt, bsum, dinv);
    scanB_kernel<<<1, 1024, 0, stream>>>(bsum, boff);
    scanC_kernel<<<NBLK_SCAN, 256, 0, stream>>>(cnt, boff, offs, cursor);
    scatter_kernel<<<(2 * E_CNT + 255) / 256, 256, 0, stream>>>(
        rows, cols, cursor, esrc, slot0, slot1);
    wprep_kernel<<<16, 256, 0, stream>>>(W, Wb);
    ep_kernel<<<EP_BLOCKS, 256, 0, stream>>>(ef, Wb, bpj, rows, cols, dinv,
                                             slot0, slot1, epw2);
    init_kernel<<<(N_CNT * 16 + 255) / 256, 256, 0, stream>>>(
        (const float4*)Gu, (const float4*)Gi, (const float4*)Gut, (const float4*)Git,
        dinv, CT0);

    u16* CTs[2] = {CT0, CT1};
    int cur = 0;
    for (int l = 0; l < N_LAYERS; l++) {
        prop_kernel<<<(N_CNT * 64 + 255) / 256, 256, 0, stream>>>(
            offs, esrc, epw2, CTs[cur], CTs[1 - cur], dinv, (l == N_LAYERS - 1) ? 1 : 0);
        cur = 1 - cur;
    }

    score_kernel<<<(B_CNT * 64 + 255) / 256, 256, 0, stream>>>(
        users, items, CTs[cur], Bu, Bi, But, Bit, Mu, out);
}